// Round 1
// baseline (612.364 us; speedup 1.0000x reference)
//
#include <hip/hip_runtime.h>
#include <hip/hip_bf16.h>

// Problem constants (from reference): N=32, T=2048, D_ENC=D_DEC=U=1024
#define NB 32
#define TD 2048
#define DIM 1024

typedef _Float16 v8h __attribute__((ext_vector_type(8)));
typedef _Float16 v4h __attribute__((ext_vector_type(4)));
typedef float    v4f __attribute__((ext_vector_type(4)));

__device__ __forceinline__ float ftanh(float x) {
    x = fminf(15.f, fmaxf(-15.f, x));
    float e = __expf(2.f * x);
    return (e - 1.f) / (e + 1.f);
}

__device__ __forceinline__ void gld_lds16(const void* g, void* l) {
    __builtin_amdgcn_global_load_lds(
        (const __attribute__((address_space(1))) unsigned int*)g,
        (__attribute__((address_space(3))) unsigned int*)l, 16, 0, 0);
}

// ---------------- K1: pq[n][u] = queries[n] . Wq[u] ----------------
__global__ __launch_bounds__(256) void pq_kernel(const float* __restrict__ q,
                                                 const float* __restrict__ Wq,
                                                 float* __restrict__ pq) {
    int wid  = blockIdx.x * 4 + (threadIdx.x >> 6);
    int lane = threadIdx.x & 63;
    int n = wid >> 10;
    int u = wid & 1023;
    const float4* qr = (const float4*)(q  + (size_t)n * DIM);
    const float4* wr = (const float4*)(Wq + (size_t)u * DIM);
    float s = 0.f;
#pragma unroll
    for (int j = 0; j < 4; ++j) {
        int i = lane + 64 * j;
        float4 a = qr[i], b = wr[i];
        s += a.x * b.x + a.y * b.y + a.z * b.z + a.w * b.w;
    }
#pragma unroll
    for (int off = 32; off >= 1; off >>= 1) s += __shfl_xor(s, off);
    if (lane == 0) pq[(size_t)n * DIM + u] = s;
}

// ---------------- K1b: f32 -> f16 conversion into workspace ----------------
__global__ __launch_bounds__(256) void cvt_kernel(const float* __restrict__ enc,
                                                  const float* __restrict__ Wk,
                                                  const int* __restrict__ lengths,
                                                  _Float16* __restrict__ ench,
                                                  _Float16* __restrict__ wkh) {
    int local = threadIdx.x * 8;              // 0..2047 within the 2-row pair
    int rsub  = local >> 10;                  // 0 or 1
    int col   = local & 1023;
    const float* src;
    _Float16* dst;
    size_t row;
    if (blockIdx.x < 32768) {
        row = (size_t)blockIdx.x * 2 + rsub;  // enc row in [0, 65536)
        int n = (int)(row >> 11), t = (int)(row & 2047);
        if (t >= lengths[n]) return;          // masked row: never read downstream
        src = enc; dst = ench;
    } else {
        row = (size_t)(blockIdx.x - 32768) * 2 + rsub;  // Wk row in [0,1024)
        src = Wk; dst = wkh;
    }
    const float4* s = (const float4*)(src + row * DIM + col);
    float4 a = s[0], b = s[1];
    v8h h;
    h[0] = (_Float16)a.x; h[1] = (_Float16)a.y; h[2] = (_Float16)a.z; h[3] = (_Float16)a.w;
    h[4] = (_Float16)b.x; h[5] = (_Float16)b.y; h[6] = (_Float16)b.z; h[7] = (_Float16)b.w;
    *(v8h*)(dst + row * DIM + col) = h;
}

// ---------------- K2 (fast v2): pipelined f16 MFMA GEMM ----------------
// One block per 128-row tile; loops all 8 bn column tiles internally.
// BK=64, double-buffered LDS, counted vmcnt(8) prefetch (T3/T4), XOR-swizzled
// LDS via pre-swizzled global source + swizzled ds_read (T2, rule #21).
// weights written once per row, no atomics. grid = (512).
#define NIT 128   // 8 bn * 16 k-steps
__global__ __launch_bounds__(256) void gemm_tanh_h2(
        const _Float16* __restrict__ ench, const _Float16* __restrict__ wkh,
        const float* __restrict__ pq, const float* __restrict__ v,
        const int* __restrict__ lengths, float* __restrict__ weights) {
    const int bm = blockIdx.x;
    const int rowBase = bm * 128;
    const int n = rowBase >> 11;
    const int tstart = rowBase & 2047;
    if (lengths[n] <= tstart) return;

    __shared__ _Float16 As[2][128 * 64];   // 16 KB x2
    __shared__ _Float16 Bs[2][128 * 64];   // 16 KB x2
    __shared__ float pq_s[DIM];            // 4 KB
    __shared__ float v_s[DIM];             // 4 KB
    __shared__ float wred[128];            // cross-wave (wn) combine

    const int tid  = threadIdx.x;
    const int lane = tid & 63;
    const int wv   = tid >> 6;
    const int wm   = wv >> 1, wn = wv & 1;   // 2x2 waves, 64x64 each
    const int q4   = lane >> 4;
    const int l16  = lane & 15;

    // staging geometry: per wave per tile, 4 issues per matrix.
    // issue = 64 lanes x 16B = 8 rows x 128B. lane l: row sr=l>>3, slot sc=l&7.
    // global source slot = sc ^ sr (inverse swizzle); LDS dest stays linear.
    const int sr  = lane >> 3;
    const int scs = (lane & 7) ^ sr;

    const _Float16* Abase = ench + (size_t)(rowBase + wv * 32 + sr) * DIM + scs * 8;
    const _Float16* Bbase = wkh + (size_t)(wv * 32 + sr) * DIM + scs * 8;

    v4f acc[4][4];
    float wacc[4][4];
    const v4f vz = {0.f, 0.f, 0.f, 0.f};
#pragma unroll
    for (int i = 0; i < 4; ++i)
#pragma unroll
        for (int j = 0; j < 4; ++j) { acc[i][j] = vz; wacc[i][j] = 0.f; }

    auto STAGE = [&](int it, int buf) {
        const int bn = it >> 4;
        const int k0 = (it & 15) << 6;
        const _Float16* Ap = Abase + k0;
        const _Float16* Bp = Bbase + (size_t)bn * (128 * DIM) + k0;
        _Float16* Al = &As[buf][(wv * 32) * 64];
        _Float16* Bl = &Bs[buf][(wv * 32) * 64];
#pragma unroll
        for (int j = 0; j < 4; ++j) {
            gld_lds16(Ap + j * 8 * DIM, Al + j * 8 * 64);
            gld_lds16(Bp + j * 8 * DIM, Bl + j * 8 * 64);
        }
    };

    // prologue: pq/v -> LDS, stage tile 0, full drain once.
#pragma unroll
    for (int i = tid; i < DIM; i += 256) {
        pq_s[i] = pq[(size_t)n * DIM + i];
        v_s[i]  = v[i];
    }
    STAGE(0, 0);
    __syncthreads();

    for (int it = 0; it < NIT; ++it) {
        const int buf = it & 1;
        if (it + 1 < NIT) {
            STAGE(it + 1, buf ^ 1);                       // prefetch stays in flight
            asm volatile("s_waitcnt vmcnt(8)" ::: "memory");  // wait current tile only
        } else {
            asm volatile("s_waitcnt vmcnt(0)" ::: "memory");
        }
        __builtin_amdgcn_sched_barrier(0);
        __builtin_amdgcn_s_barrier();                     // tile[buf] visible to all
        __builtin_amdgcn_sched_barrier(0);

#pragma unroll
        for (int kk = 0; kk < 2; ++kk) {
            v8h a[4], b[4];
#pragma unroll
            for (int mt = 0; mt < 4; ++mt) {
                int r = wm * 64 + mt * 16 + l16;
                a[mt] = *(const v8h*)(&As[buf][r * 64 + (((kk * 4 + q4) ^ (r & 7)) * 8)]);
            }
#pragma unroll
            for (int nt = 0; nt < 4; ++nt) {
                int r = wn * 64 + nt * 16 + l16;
                b[nt] = *(const v8h*)(&Bs[buf][r * 64 + (((kk * 4 + q4) ^ (r & 7)) * 8)]);
            }
#pragma unroll
            for (int mt = 0; mt < 4; ++mt)
#pragma unroll
                for (int nt = 0; nt < 4; ++nt)
                    acc[mt][nt] = __builtin_amdgcn_mfma_f32_16x16x32_f16(
                        a[mt], b[nt], acc[mt][nt], 0, 0, 0);
        }

        if ((it & 15) == 15) {      // bn finished: fold tanh()*v into wacc, reset acc
            const int bn = it >> 4;
            float pqv[4], vv[4];
#pragma unroll
            for (int nt = 0; nt < 4; ++nt) {
                int ug = bn * 128 + wn * 64 + nt * 16 + l16;
                pqv[nt] = pq_s[ug];
                vv[nt]  = v_s[ug];
            }
#pragma unroll
            for (int mt = 0; mt < 4; ++mt)
#pragma unroll
                for (int r = 0; r < 4; ++r) {
                    float s = 0.f;
#pragma unroll
                    for (int nt = 0; nt < 4; ++nt)
                        s += ftanh(acc[mt][nt][r] + pqv[nt]) * vv[nt];
                    wacc[mt][r] += s;
                }
#pragma unroll
            for (int mt = 0; mt < 4; ++mt)
#pragma unroll
                for (int nt = 0; nt < 4; ++nt) acc[mt][nt] = vz;
        }

        __builtin_amdgcn_sched_barrier(0);
        __builtin_amdgcn_s_barrier();                     // all reads of buf done
        __builtin_amdgcn_sched_barrier(0);
    }

    // epilogue: reduce over the 16 u-lanes, combine wn pair, one plain store.
#pragma unroll
    for (int mt = 0; mt < 4; ++mt)
#pragma unroll
        for (int r = 0; r < 4; ++r) {
            float s = wacc[mt][r];
            s += __shfl_xor(s, 1);
            s += __shfl_xor(s, 2);
            s += __shfl_xor(s, 4);
            s += __shfl_xor(s, 8);
            wacc[mt][r] = s;
        }
    if (wn == 1 && l16 == 0) {
#pragma unroll
        for (int mt = 0; mt < 4; ++mt)
#pragma unroll
            for (int r = 0; r < 4; ++r)
                wred[wm * 64 + mt * 16 + q4 * 4 + r] = wacc[mt][r];
    }
    __syncthreads();
    if (wn == 0 && l16 == 0) {
#pragma unroll
        for (int mt = 0; mt < 4; ++mt)
#pragma unroll
            for (int r = 0; r < 4; ++r) {
                int R = rowBase + wm * 64 + mt * 16 + q4 * 4 + r;
                weights[R] = wacc[mt][r] + wred[wm * 64 + mt * 16 + q4 * 4 + r];
            }
    }
}

// ---------------- K2 (fallback): inline-convert f32 GEMM ----------------
__global__ __launch_bounds__(256) void gemm_tanh_kernel(
        const float* __restrict__ enc, const float* __restrict__ Wk,
        const float* __restrict__ pq,  const float* __restrict__ v,
        const int* __restrict__ lengths, float* __restrict__ weights) {
    const int bm = blockIdx.x;
    const int bn = blockIdx.y;
    const int rowBase = bm * 128;
    const int n = rowBase >> 11;
    const int tstart = rowBase & 2047;
    if (lengths[n] <= tstart) return;

    __shared__ _Float16 As[128 * 40];
    __shared__ _Float16 Bs[128 * 40];

    const int tid  = threadIdx.x;
    const int lane = tid & 63;
    const int wv   = tid >> 6;
    const int wm   = wv >> 1, wn = wv & 1;
    const int q4   = lane >> 4;
    const int l16  = lane & 15;

    v4f acc[4][4];
    const v4f vz = {0.f, 0.f, 0.f, 0.f};
#pragma unroll
    for (int i = 0; i < 4; ++i)
#pragma unroll
        for (int j = 0; j < 4; ++j) acc[i][j] = vz;

    const int srow = tid >> 3;
    const int skc  = (tid & 7) * 4;

    for (int k0 = 0; k0 < DIM; k0 += 32) {
        __syncthreads();
#pragma unroll
        for (int j = 0; j < 4; ++j) {
            int row = j * 32 + srow;
            float4 av = *(const float4*)(enc + (size_t)(rowBase + row) * DIM + k0 + skc);
            v4h ah;
            ah.x = (_Float16)av.x; ah.y = (_Float16)av.y;
            ah.z = (_Float16)av.z; ah.w = (_Float16)av.w;
            *(v4h*)(&As[row * 40 + skc]) = ah;
            float4 bv = *(const float4*)(Wk + (size_t)(bn * 128 + row) * DIM + k0 + skc);
            v4h bh;
            bh.x = (_Float16)bv.x; bh.y = (_Float16)bv.y;
            bh.z = (_Float16)bv.z; bh.w = (_Float16)bv.w;
            *(v4h*)(&Bs[row * 40 + skc]) = bh;
        }
        __syncthreads();

        v8h afr[4], bfr[4];
#pragma unroll
        for (int mt = 0; mt < 4; ++mt)
            afr[mt] = *(const v8h*)(&As[(wm * 64 + mt * 16 + l16) * 40 + q4 * 8]);
#pragma unroll
        for (int nt = 0; nt < 4; ++nt)
            bfr[nt] = *(const v8h*)(&Bs[(wn * 64 + nt * 16 + l16) * 40 + q4 * 8]);
#pragma unroll
        for (int mt = 0; mt < 4; ++mt)
#pragma unroll
            for (int nt = 0; nt < 4; ++nt)
                acc[mt][nt] = __builtin_amdgcn_mfma_f32_16x16x32_f16(
                    afr[mt], bfr[nt], acc[mt][nt], 0, 0, 0);
    }

    float pqv[4], vv[4];
#pragma unroll
    for (int nt = 0; nt < 4; ++nt) {
        int ug = bn * 128 + wn * 64 + nt * 16 + l16;
        pqv[nt] = pq[(size_t)n * DIM + ug];
        vv[nt]  = v[ug];
    }
#pragma unroll
    for (int mt = 0; mt < 4; ++mt) {
#pragma unroll
        for (int r = 0; r < 4; ++r) {
            float s = 0.f;
#pragma unroll
            for (int nt = 0; nt < 4; ++nt)
                s += ftanh(acc[mt][nt][r] + pqv[nt]) * vv[nt];
            s += __shfl_xor(s, 1);
            s += __shfl_xor(s, 2);
            s += __shfl_xor(s, 4);
            s += __shfl_xor(s, 8);
            if (l16 == 0) {
                int R = rowBase + wm * 64 + mt * 16 + q4 * 4 + r;
                atomicAdd(&weights[R], s);
            }
        }
    }
}

// ---------------- K3: masked softmax per n-row, in place ----------------
__global__ __launch_bounds__(256) void softmax_kernel(float* __restrict__ w,
                                                      const int* __restrict__ lengths) {
    int n = blockIdx.x;
    int len = lengths[n];
    float* row = w + (size_t)n * TD;
    int tid = threadIdx.x;
    float wv[8], ev[8];
    float mx = -INFINITY;
#pragma unroll
    for (int i = 0; i < 8; ++i) {
        int t = tid + i * 256;
        float x = row[t];
        x = (t < len) ? x : -INFINITY;
        wv[i] = x;
        mx = fmaxf(mx, x);
    }
#pragma unroll
    for (int off = 32; off >= 1; off >>= 1) mx = fmaxf(mx, __shfl_xor(mx, off));
    __shared__ float redm[4], reds[4];
    int lane = tid & 63, wvid = tid >> 6;
    if (lane == 0) redm[wvid] = mx;
    __syncthreads();
    mx = fmaxf(fmaxf(redm[0], redm[1]), fmaxf(redm[2], redm[3]));
    float sm = 0.f;
#pragma unroll
    for (int i = 0; i < 8; ++i) { ev[i] = __expf(wv[i] - mx); sm += ev[i]; }
#pragma unroll
    for (int off = 32; off >= 1; off >>= 1) sm += __shfl_xor(sm, off);
    if (lane == 0) reds[wvid] = sm;
    __syncthreads();
    sm = reds[0] + reds[1] + reds[2] + reds[3];
    float inv = 1.f / sm;
#pragma unroll
    for (int i = 0; i < 8; ++i) row[tid + i * 256] = ev[i] * inv;
}

// ---------------- K4 (fast v2): contexts, 256-t chunks, 16B loads ----------------
// 8 blocks per n (vs 64): register accumulation over up to 256 rows,
// halves combined through LDS -> 8 atomics per output element.
__global__ __launch_bounds__(256) void ctx_kernel_h2(const float* __restrict__ align,
                                                     const _Float16* __restrict__ ench,
                                                     const int* __restrict__ lengths,
                                                     float* __restrict__ ctx) {
    int n  = blockIdx.y;
    int t0 = blockIdx.x * 256;
    int len = lengths[n];
    if (len <= t0) return;
    int half = threadIdx.x >> 7;          // 0/1: t parity
    int col  = (threadIdx.x & 127) * 8;   // 8 cols -> 16B f16 loads
    float acc[8];
#pragma unroll
    for (int i = 0; i < 8; ++i) acc[i] = 0.f;
    int tend = min(t0 + 256, len);        // only converted (valid) rows
    const float* arow = align + (size_t)n * TD;
    const _Float16* ebase = ench + (size_t)n * TD * DIM + col;
    for (int t = t0 + half; t < tend; t += 2) {
        float a = arow[t];
        v8h e = *(const v8h*)(ebase + (size_t)t * DIM);
#pragma unroll
        for (int i = 0; i < 8; ++i) acc[i] += a * (float)e[i];
    }
    __shared__ float cred[DIM];
    if (half == 1) {
#pragma unroll
        for (int i = 0; i < 8; ++i) cred[col + i] = acc[i];
    }
    __syncthreads();
    if (half == 0) {
        float* c = ctx + (size_t)n * DIM + col;
#pragma unroll
        for (int i = 0; i < 8; ++i) atomicAdd(c + i, acc[i] + cred[col + i]);
    }
}

// ---------------- K4 (fallback): f32 enc ----------------
__global__ __launch_bounds__(256) void ctx_kernel(const float* __restrict__ align,
                                                  const float* __restrict__ enc,
                                                  const int* __restrict__ lengths,
                                                  float* __restrict__ ctx) {
    int n  = blockIdx.y;
    int t0 = blockIdx.x * 128;
    if (lengths[n] <= t0) return;
    int e = threadIdx.x * 4;
    float4 acc = make_float4(0.f, 0.f, 0.f, 0.f);
    const float* arow = align + (size_t)n * TD;
    const float* erow = enc + (size_t)n * TD * DIM;
    for (int tt = 0; tt < 128; ++tt) {
        int t = t0 + tt;
        float a = arow[t];
        if (a != 0.f) {
            float4 evv = *(const float4*)(erow + (size_t)t * DIM + e);
            acc.x += a * evv.x; acc.y += a * evv.y;
            acc.z += a * evv.z; acc.w += a * evv.w;
        }
    }
    float* c = ctx + (size_t)n * DIM + e;
    atomicAdd(c + 0, acc.x);
    atomicAdd(c + 1, acc.y);
    atomicAdd(c + 2, acc.z);
    atomicAdd(c + 3, acc.w);
}

extern "C" void kernel_launch(void* const* d_in, const int* in_sizes, int n_in,
                              void* d_out, int out_size, void* d_ws, size_t ws_size,
                              hipStream_t stream) {
    const float* queries = (const float*)d_in[0];   // [32,1,1024]
    const float* enc     = (const float*)d_in[1];   // [32,2048,1024]
    const int*   lengths = (const int*)d_in[2];     // [32]
    const float* v       = (const float*)d_in[3];   // [1024]
    const float* Wq      = (const float*)d_in[4];   // [1024,1024]
    const float* Wk      = (const float*)d_in[5];   // [1024,1024]

    float* out = (float*)d_out;
    float* ctx = out;                // [32,1024]  (also temp home of pq)
    float* alg = out + NB * DIM;     // [32,2048]  (weights -> alignments in place)
    float* pq  = ctx;                // pq fully consumed before ctx memset below
    (void)in_sizes; (void)n_in; (void)out_size;

    const size_t ench_elems = (size_t)NB * TD * DIM;
    const size_t need = (ench_elems + (size_t)DIM * DIM) * sizeof(_Float16);

    pq_kernel<<<NB * DIM / 4, 256, 0, stream>>>(queries, Wq, pq);

    if (ws_size >= need) {
        _Float16* ench = (_Float16*)d_ws;
        _Float16* wkh  = ench + ench_elems;
        cvt_kernel<<<32768 + 512, 256, 0, stream>>>(enc, Wk, lengths, ench, wkh);
        // no alg memset needed: gemm_tanh_h2 writes every row it owns non-atomically,
        // softmax masks t >= len itself.
        gemm_tanh_h2<<<512, 256, 0, stream>>>(ench, wkh, pq, v, lengths, alg);
        softmax_kernel<<<NB, 256, 0, stream>>>(alg, lengths);
        hipMemsetAsync(ctx, 0, (size_t)NB * DIM * sizeof(float), stream);
        ctx_kernel_h2<<<dim3(8, NB), 256, 0, stream>>>(alg, ench, lengths, ctx);
    } else {
        hipMemsetAsync(alg, 0, (size_t)NB * TD * sizeof(float), stream);
        dim3 g2(512, 8);
        gemm_tanh_kernel<<<g2, 256, 0, stream>>>(enc, Wk, pq, v, lengths, alg);
        softmax_kernel<<<NB, 256, 0, stream>>>(alg, lengths);
        hipMemsetAsync(ctx, 0, (size_t)NB * DIM * sizeof(float), stream);
        ctx_kernel<<<dim3(16, NB), 256, 0, stream>>>(alg, enc, lengths, ctx);
    }
}

// Round 2
// 517.718 us; speedup vs baseline: 1.1828x; 1.1828x over previous
//
#include <hip/hip_runtime.h>
#include <hip/hip_bf16.h>

// Problem constants (from reference): N=32, T=2048, D_ENC=D_DEC=U=1024
#define NB 32
#define TD 2048
#define DIM 1024

typedef _Float16 v8h __attribute__((ext_vector_type(8)));
typedef _Float16 v4h __attribute__((ext_vector_type(4)));
typedef float    v4f __attribute__((ext_vector_type(4)));

__device__ __forceinline__ float ftanh(float x) {
    x = fminf(15.f, fmaxf(-15.f, x));
    float e = __expf(2.f * x);
    return (e - 1.f) / (e + 1.f);
}

__device__ __forceinline__ void gld_lds16(const void* g, void* l) {
    __builtin_amdgcn_global_load_lds(
        (const __attribute__((address_space(1))) unsigned int*)g,
        (__attribute__((address_space(3))) unsigned int*)l, 16, 0, 0);
}

// ---------------- K1: pq[n][u] = queries[n] . Wq[u] ----------------
__global__ __launch_bounds__(256) void pq_kernel(const float* __restrict__ q,
                                                 const float* __restrict__ Wq,
                                                 float* __restrict__ pq) {
    int wid  = blockIdx.x * 4 + (threadIdx.x >> 6);
    int lane = threadIdx.x & 63;
    int n = wid >> 10;
    int u = wid & 1023;
    const float4* qr = (const float4*)(q  + (size_t)n * DIM);
    const float4* wr = (const float4*)(Wq + (size_t)u * DIM);
    float s = 0.f;
#pragma unroll
    for (int j = 0; j < 4; ++j) {
        int i = lane + 64 * j;
        float4 a = qr[i], b = wr[i];
        s += a.x * b.x + a.y * b.y + a.z * b.z + a.w * b.w;
    }
#pragma unroll
    for (int off = 32; off >= 1; off >>= 1) s += __shfl_xor(s, off);
    if (lane == 0) pq[(size_t)n * DIM + u] = s;
}

// ---------------- K1b: f32 -> f16 conversion into workspace ----------------
__global__ __launch_bounds__(256) void cvt_kernel(const float* __restrict__ enc,
                                                  const float* __restrict__ Wk,
                                                  const int* __restrict__ lengths,
                                                  _Float16* __restrict__ ench,
                                                  _Float16* __restrict__ wkh) {
    int local = threadIdx.x * 8;              // 0..2047 within the 2-row pair
    int rsub  = local >> 10;                  // 0 or 1
    int col   = local & 1023;
    const float* src;
    _Float16* dst;
    size_t row;
    if (blockIdx.x < 32768) {
        row = (size_t)blockIdx.x * 2 + rsub;  // enc row in [0, 65536)
        int n = (int)(row >> 11), t = (int)(row & 2047);
        if (t >= lengths[n]) return;          // masked row: never read downstream
        src = enc; dst = ench;
    } else {
        row = (size_t)(blockIdx.x - 32768) * 2 + rsub;  // Wk row in [0,1024)
        src = Wk; dst = wkh;
    }
    const float4* s = (const float4*)(src + row * DIM + col);
    float4 a = s[0], b = s[1];
    v8h h;
    h[0] = (_Float16)a.x; h[1] = (_Float16)a.y; h[2] = (_Float16)a.z; h[3] = (_Float16)a.w;
    h[4] = (_Float16)b.x; h[5] = (_Float16)b.y; h[6] = (_Float16)b.z; h[7] = (_Float16)b.w;
    *(v8h*)(dst + row * DIM + col) = h;
}

// ---------------- K2 (fast v3): m97-style single-buffer, BK=64, swizzled ----------------
// grid = 4096 (1-D). Per block: one 128x128 output tile (bm, bn).
// XCD-balanced swizzle: bm = ((idx>>3)<<3)|xcd  -> every XCD sees all n values
// (length-balanced), and the 8 bn-blocks of one bm are CONSECUTIVE on one XCD
// so the 256 KB A-tile is L2-resident across its 8 uses.
// LDS 32 KB -> 5 blocks/CU; latency hidden by TLP (m97 evidence), not pipelining.
// T2 swizzle identical to round-1 (measured 0 bank conflicts).
__global__ __launch_bounds__(256) void gemm_tanh_h3(
        const _Float16* __restrict__ ench, const _Float16* __restrict__ wkh,
        const float* __restrict__ pq, const float* __restrict__ v,
        const int* __restrict__ lengths, float* __restrict__ weights) {
    const int bid = blockIdx.x;
    const int xcd = bid & 7;
    const int idx = bid >> 3;
    const int bm  = ((idx >> 3) << 3) | xcd;   // [0,512), ≡ xcd (mod 8)
    const int bn  = idx & 7;
    const int rowBase = bm * 128;
    const int n = rowBase >> 11;
    const int tstart = rowBase & 2047;
    if (lengths[n] <= tstart) return;

    __shared__ _Float16 As[128 * 64];   // 16 KB
    __shared__ _Float16 Bs[128 * 64];   // 16 KB

    const int tid  = threadIdx.x;
    const int lane = tid & 63;
    const int wv   = tid >> 6;
    const int wm   = wv >> 1, wn = wv & 1;   // 2x2 waves, 64x64 each
    const int q4   = lane >> 4;
    const int l16  = lane & 15;

    // staging: per wave 4 issues per matrix per K-step; issue = 8 rows x 128B.
    // lane l -> row sr=l>>3, LDS slot sl=l&7; global slot pre-swizzled sl^sr
    // so that LDS[r][s] = G[r][s ^ (r&7)] with a LINEAR LDS dest (rule #21).
    const int sr  = lane >> 3;
    const int scs = (lane & 7) ^ sr;

    const _Float16* Ag = ench + (size_t)(rowBase + wv * 32 + sr) * DIM + scs * 8;
    const _Float16* Bg = wkh + (size_t)(bn * 128 + wv * 32 + sr) * DIM + scs * 8;
    _Float16* Al = &As[(wv * 32) * 64];
    _Float16* Bl = &Bs[(wv * 32) * 64];

    v4f acc[4][4];
    const v4f vz = {0.f, 0.f, 0.f, 0.f};
#pragma unroll
    for (int i = 0; i < 4; ++i)
#pragma unroll
        for (int j = 0; j < 4; ++j) acc[i][j] = vz;

    for (int k0 = 0; k0 < DIM; k0 += 64) {
        __syncthreads();                       // all reads of LDS done
#pragma unroll
        for (int j = 0; j < 4; ++j) {
            gld_lds16(Ag + k0 + j * 8 * DIM, Al + j * 8 * 64);
            gld_lds16(Bg + k0 + j * 8 * DIM, Bl + j * 8 * 64);
        }
        __syncthreads();                       // drains vmcnt(0): tile visible

#pragma unroll
        for (int kk = 0; kk < 2; ++kk) {
            v8h a[4], b[4];
#pragma unroll
            for (int mt = 0; mt < 4; ++mt) {
                int r = wm * 64 + mt * 16 + l16;
                a[mt] = *(const v8h*)(&As[r * 64 + (((kk * 4 + q4) ^ (r & 7)) * 8)]);
            }
#pragma unroll
            for (int nt = 0; nt < 4; ++nt) {
                int r = wn * 64 + nt * 16 + l16;
                b[nt] = *(const v8h*)(&Bs[r * 64 + (((kk * 4 + q4) ^ (r & 7)) * 8)]);
            }
#pragma unroll
            for (int mt = 0; mt < 4; ++mt)
#pragma unroll
                for (int nt = 0; nt < 4; ++nt)
                    acc[mt][nt] = __builtin_amdgcn_mfma_f32_16x16x32_f16(
                        a[mt], b[nt], acc[mt][nt], 0, 0, 0);
        }
    }

    float pqv[4], vv[4];
#pragma unroll
    for (int nt = 0; nt < 4; ++nt) {
        int ug = bn * 128 + wn * 64 + nt * 16 + l16;
        pqv[nt] = pq[(size_t)n * DIM + ug];
        vv[nt]  = v[ug];
    }
#pragma unroll
    for (int mt = 0; mt < 4; ++mt) {
#pragma unroll
        for (int r = 0; r < 4; ++r) {
            float s = 0.f;
#pragma unroll
            for (int nt = 0; nt < 4; ++nt)
                s += ftanh(acc[mt][nt][r] + pqv[nt]) * vv[nt];
            s += __shfl_xor(s, 1);
            s += __shfl_xor(s, 2);
            s += __shfl_xor(s, 4);
            s += __shfl_xor(s, 8);
            if (l16 == 0) {
                int R = rowBase + wm * 64 + mt * 16 + q4 * 4 + r;
                atomicAdd(&weights[R], s);
            }
        }
    }
}

// ---------------- K2 (fallback): inline-convert f32 GEMM ----------------
__global__ __launch_bounds__(256) void gemm_tanh_kernel(
        const float* __restrict__ enc, const float* __restrict__ Wk,
        const float* __restrict__ pq,  const float* __restrict__ v,
        const int* __restrict__ lengths, float* __restrict__ weights) {
    const int bm = blockIdx.x;
    const int bn = blockIdx.y;
    const int rowBase = bm * 128;
    const int n = rowBase >> 11;
    const int tstart = rowBase & 2047;
    if (lengths[n] <= tstart) return;

    __shared__ _Float16 As[128 * 40];
    __shared__ _Float16 Bs[128 * 40];

    const int tid  = threadIdx.x;
    const int lane = tid & 63;
    const int wv   = tid >> 6;
    const int wm   = wv >> 1, wn = wv & 1;
    const int q4   = lane >> 4;
    const int l16  = lane & 15;

    v4f acc[4][4];
    const v4f vz = {0.f, 0.f, 0.f, 0.f};
#pragma unroll
    for (int i = 0; i < 4; ++i)
#pragma unroll
        for (int j = 0; j < 4; ++j) acc[i][j] = vz;

    const int srow = tid >> 3;
    const int skc  = (tid & 7) * 4;

    for (int k0 = 0; k0 < DIM; k0 += 32) {
        __syncthreads();
#pragma unroll
        for (int j = 0; j < 4; ++j) {
            int row = j * 32 + srow;
            float4 av = *(const float4*)(enc + (size_t)(rowBase + row) * DIM + k0 + skc);
            v4h ah;
            ah.x = (_Float16)av.x; ah.y = (_Float16)av.y;
            ah.z = (_Float16)av.z; ah.w = (_Float16)av.w;
            *(v4h*)(&As[row * 40 + skc]) = ah;
            float4 bv = *(const float4*)(Wk + (size_t)(bn * 128 + row) * DIM + k0 + skc);
            v4h bh;
            bh.x = (_Float16)bv.x; bh.y = (_Float16)bv.y;
            bh.z = (_Float16)bv.z; bh.w = (_Float16)bv.w;
            *(v4h*)(&Bs[row * 40 + skc]) = bh;
        }
        __syncthreads();

        v8h afr[4], bfr[4];
#pragma unroll
        for (int mt = 0; mt < 4; ++mt)
            afr[mt] = *(const v8h*)(&As[(wm * 64 + mt * 16 + l16) * 40 + q4 * 8]);
#pragma unroll
        for (int nt = 0; nt < 4; ++nt)
            bfr[nt] = *(const v8h*)(&Bs[(wn * 64 + nt * 16 + l16) * 40 + q4 * 8]);
#pragma unroll
        for (int mt = 0; mt < 4; ++mt)
#pragma unroll
            for (int nt = 0; nt < 4; ++nt)
                acc[mt][nt] = __builtin_amdgcn_mfma_f32_16x16x32_f16(
                    afr[mt], bfr[nt], acc[mt][nt], 0, 0, 0);
    }

    float pqv[4], vv[4];
#pragma unroll
    for (int nt = 0; nt < 4; ++nt) {
        int ug = bn * 128 + wn * 64 + nt * 16 + l16;
        pqv[nt] = pq[(size_t)n * DIM + ug];
        vv[nt]  = v[ug];
    }
#pragma unroll
    for (int mt = 0; mt < 4; ++mt) {
#pragma unroll
        for (int r = 0; r < 4; ++r) {
            float s = 0.f;
#pragma unroll
            for (int nt = 0; nt < 4; ++nt)
                s += ftanh(acc[mt][nt][r] + pqv[nt]) * vv[nt];
            s += __shfl_xor(s, 1);
            s += __shfl_xor(s, 2);
            s += __shfl_xor(s, 4);
            s += __shfl_xor(s, 8);
            if (l16 == 0) {
                int R = rowBase + wm * 64 + mt * 16 + q4 * 4 + r;
                atomicAdd(&weights[R], s);
            }
        }
    }
}

// ---------------- K3: masked softmax per n-row, in place ----------------
__global__ __launch_bounds__(256) void softmax_kernel(float* __restrict__ w,
                                                      const int* __restrict__ lengths) {
    int n = blockIdx.x;
    int len = lengths[n];
    float* row = w + (size_t)n * TD;
    int tid = threadIdx.x;
    float wv[8], ev[8];
    float mx = -INFINITY;
#pragma unroll
    for (int i = 0; i < 8; ++i) {
        int t = tid + i * 256;
        float x = row[t];
        x = (t < len) ? x : -INFINITY;
        wv[i] = x;
        mx = fmaxf(mx, x);
    }
#pragma unroll
    for (int off = 32; off >= 1; off >>= 1) mx = fmaxf(mx, __shfl_xor(mx, off));
    __shared__ float redm[4], reds[4];
    int lane = tid & 63, wvid = tid >> 6;
    if (lane == 0) redm[wvid] = mx;
    __syncthreads();
    mx = fmaxf(fmaxf(redm[0], redm[1]), fmaxf(redm[2], redm[3]));
    float sm = 0.f;
#pragma unroll
    for (int i = 0; i < 8; ++i) { ev[i] = __expf(wv[i] - mx); sm += ev[i]; }
#pragma unroll
    for (int off = 32; off >= 1; off >>= 1) sm += __shfl_xor(sm, off);
    if (lane == 0) reds[wvid] = sm;
    __syncthreads();
    sm = reds[0] + reds[1] + reds[2] + reds[3];
    float inv = 1.f / sm;
#pragma unroll
    for (int i = 0; i < 8; ++i) row[tid + i * 256] = ev[i] * inv;
}

// ---------------- K4 (fast v3): contexts, 128-t chunks, 16B loads ----------------
// 16 blocks per n: register accumulation over up to 128 rows (2-way t-split),
// halves combined through LDS -> 16 atomics per output element.
__global__ __launch_bounds__(256) void ctx_kernel_h3(const float* __restrict__ align,
                                                     const _Float16* __restrict__ ench,
                                                     const int* __restrict__ lengths,
                                                     float* __restrict__ ctx) {
    int n  = blockIdx.y;
    int t0 = blockIdx.x * 128;
    int len = lengths[n];
    if (len <= t0) return;
    int half = threadIdx.x >> 7;          // 0/1: t parity
    int col  = (threadIdx.x & 127) * 8;   // 8 cols -> 16B f16 loads
    float acc[8];
#pragma unroll
    for (int i = 0; i < 8; ++i) acc[i] = 0.f;
    int tend = min(t0 + 128, len);        // only converted (valid) rows
    const float* arow = align + (size_t)n * TD;
    const _Float16* ebase = ench + (size_t)n * TD * DIM + col;
    for (int t = t0 + half; t < tend; t += 2) {
        float a = arow[t];
        v8h e = *(const v8h*)(ebase + (size_t)t * DIM);
#pragma unroll
        for (int i = 0; i < 8; ++i) acc[i] += a * (float)e[i];
    }
    __shared__ float cred[DIM];
    if (half == 1) {
#pragma unroll
        for (int i = 0; i < 8; ++i) cred[col + i] = acc[i];
    }
    __syncthreads();
    if (half == 0) {
        float* c = ctx + (size_t)n * DIM + col;
#pragma unroll
        for (int i = 0; i < 8; ++i) atomicAdd(c + i, acc[i] + cred[col + i]);
    }
}

// ---------------- K4 (fallback): f32 enc ----------------
__global__ __launch_bounds__(256) void ctx_kernel(const float* __restrict__ align,
                                                  const float* __restrict__ enc,
                                                  const int* __restrict__ lengths,
                                                  float* __restrict__ ctx) {
    int n  = blockIdx.y;
    int t0 = blockIdx.x * 128;
    if (lengths[n] <= t0) return;
    int e = threadIdx.x * 4;
    float4 acc = make_float4(0.f, 0.f, 0.f, 0.f);
    const float* arow = align + (size_t)n * TD;
    const float* erow = enc + (size_t)n * TD * DIM;
    for (int tt = 0; tt < 128; ++tt) {
        int t = t0 + tt;
        float a = arow[t];
        if (a != 0.f) {
            float4 evv = *(const float4*)(erow + (size_t)t * DIM + e);
            acc.x += a * evv.x; acc.y += a * evv.y;
            acc.z += a * evv.z; acc.w += a * evv.w;
        }
    }
    float* c = ctx + (size_t)n * DIM + e;
    atomicAdd(c + 0, acc.x);
    atomicAdd(c + 1, acc.y);
    atomicAdd(c + 2, acc.z);
    atomicAdd(c + 3, acc.w);
}

extern "C" void kernel_launch(void* const* d_in, const int* in_sizes, int n_in,
                              void* d_out, int out_size, void* d_ws, size_t ws_size,
                              hipStream_t stream) {
    const float* queries = (const float*)d_in[0];   // [32,1,1024]
    const float* enc     = (const float*)d_in[1];   // [32,2048,1024]
    const int*   lengths = (const int*)d_in[2];     // [32]
    const float* v       = (const float*)d_in[3];   // [1024]
    const float* Wq      = (const float*)d_in[4];   // [1024,1024]
    const float* Wk      = (const float*)d_in[5];   // [1024,1024]

    float* out = (float*)d_out;
    float* ctx = out;                // [32,1024]  (also temp home of pq)
    float* alg = out + NB * DIM;     // [32,2048]  (weights -> alignments in place)
    float* pq  = ctx;                // pq fully consumed before ctx memset below
    (void)in_sizes; (void)n_in; (void)out_size;

    const size_t ench_elems = (size_t)NB * TD * DIM;
    const size_t need = (ench_elems + (size_t)DIM * DIM) * sizeof(_Float16);

    hipMemsetAsync(alg, 0, (size_t)NB * TD * sizeof(float), stream);
    pq_kernel<<<NB * DIM / 4, 256, 0, stream>>>(queries, Wq, pq);

    if (ws_size >= need) {
        _Float16* ench = (_Float16*)d_ws;
        _Float16* wkh  = ench + ench_elems;
        cvt_kernel<<<32768 + 512, 256, 0, stream>>>(enc, Wk, lengths, ench, wkh);
        gemm_tanh_h3<<<4096, 256, 0, stream>>>(ench, wkh, pq, v, lengths, alg);
        softmax_kernel<<<NB, 256, 0, stream>>>(alg, lengths);
        hipMemsetAsync(ctx, 0, (size_t)NB * DIM * sizeof(float), stream);
        ctx_kernel_h3<<<dim3(16, NB), 256, 0, stream>>>(alg, ench, lengths, ctx);
    } else {
        dim3 g2(512, 8);
        gemm_tanh_kernel<<<g2, 256, 0, stream>>>(enc, Wk, pq, v, lengths, alg);
        softmax_kernel<<<NB, 256, 0, stream>>>(alg, lengths);
        hipMemsetAsync(ctx, 0, (size_t)NB * DIM * sizeof(float), stream);
        ctx_kernel<<<dim3(16, NB), 256, 0, stream>>>(alg, enc, lengths, ctx);
    }
}